// Round 13
// baseline (201.492 us; speedup 1.0000x reference)
//
#include <hip/hip_runtime.h>

typedef float f32x4 __attribute__((ext_vector_type(4)));
typedef int   i32x4 __attribute__((ext_vector_type(4)));
typedef int   i32x8 __attribute__((ext_vector_type(8)));
typedef unsigned short ushort_t;

#define T_LEN 128
#define BATCH 64
#define M_TOK 8192            // BATCH * T_LEN
#define HDIM  128
#define NGRP  64              // 64 groups of 128 tokens
#define NBLK  (NGRP * (NGRP + 1) / 2)   // 2080 triangle blocks
#define SQRT_LOG2E 1.2011224087864498f  // (s*xi).(s*xj) = log2(e)*xi.xj

// 2^t Taylor deg-4 (|t| <= ~0.5: max abs err ~4e-5)
#define P_C1 0.6931471806f
#define P_C2 0.2402265070f
#define P_C3 0.0555041087f
#define P_C4 0.0096181291f

// Fragment-major layout for 16x16x128 f8f6f4 MFMA:
// xsw[T][quad][col][32B]  (strides 2048 / 512 / 32 bytes)
// = bytes [quad*32, quad*32+32) of token (16*T + col), fp8 e4m3, pre-scaled.

// Kernel A: fp8 convert into fragment-major layout + fp32-exact pos_i.
// Zeroes part[] (8192 floats, atomic target) and the completion counter.
__global__ __launch_bounds__(256) void prep_kernel(const float* __restrict__ hs,
                                                   unsigned char* __restrict__ xsw,
                                                   float* __restrict__ pos,
                                                   float* __restrict__ part,
                                                   unsigned int* __restrict__ counter) {
    int wave = threadIdx.x >> 6;
    int lane = threadIdx.x & 63;
    int i = blockIdx.x * 4 + wave;
    int t = i & (T_LEN - 1);
    const float* row = hs + (size_t)i * HDIM;
    float2 x = *(const float2*)(row + 2 * lane);
    unsigned int pk = __builtin_amdgcn_cvt_pk_fp8_f32(x.x * SQRT_LOG2E,
                                                      x.y * SQRT_LOG2E, 0, false);
    {
        int T   = i >> 4;
        int c   = i & 15;
        int qd  = lane >> 4;            // (2*lane) / 32
        int off = (2 * lane) & 31;      // within the 32B chunk (even)
        *(ushort_t*)(xsw + (size_t)T * 2048 + qd * 512 + c * 32 + off) = (ushort_t)pk;
    }
    float acc = 0.f;
    if (t > 0) {
        float2 p = *(const float2*)(row - HDIM + 2 * lane);
        acc += x.x * p.x + x.y * p.y;
    }
    if (t < T_LEN - 1) {
        float2 n = *(const float2*)(row + HDIM + 2 * lane);
        acc += x.x * n.x + x.y * n.y;
    }
    for (int m = 32; m; m >>= 1) acc += __shfl_xor(acc, m);
    if (lane == 0) pos[i] = acc;
    if (threadIdx.x < 4) part[blockIdx.x * 4 + threadIdx.x] = 0.f;
    if (blockIdx.x == 0 && threadIdx.x == 0) counter[0] = 0u;
}

__device__ inline i32x8 load_frag32(const unsigned char* p) {
    i32x4 lo = *(const i32x4*)p;
    i32x4 hi = *(const i32x4*)(p + 16);
    return __builtin_shufflevector(lo, hi, 0, 1, 2, 3, 4, 5, 6, 7);
}

// Kernel B (R13): triangle gram, max-ILP. Block (ti,tj) handles 128x128;
// wave w: 32 rows (2 A frags) x 8 col-tiles. ALL 8 B fragments (64 VGPRs)
// are loaded upfront -> ONE ~400-cyc latency exposure per block instead of
// 8 x ~230 (R12's depth-2 ring was the latency leak; work/traffic cuts
// didn't move the needle because blocks are latency-bound).
// Closed-form triangle decode (R12 had a <=64-iter SALU loop).
// Row/col sums -> part[8192] via POST-LOOP atomics (R11's failure was
// in-loop same-line atomics; these are 532k adds over 512 lines, spread).
// Last-finishing block (device counter) computes the final loss.
__global__ __launch_bounds__(256) void negsum_kernel(const unsigned char* __restrict__ xsw,
                                                     float* __restrict__ part,
                                                     const float* __restrict__ pos,
                                                     const int* __restrict__ dia,
                                                     unsigned int* __restrict__ counter,
                                                     float* __restrict__ out) {
    __shared__ float sred[4];
    __shared__ int   scnt[4];
    __shared__ int   sdia[BATCH];
    __shared__ int   slast;
    int tid  = threadIdx.x;
    int wave = tid >> 6;
    int lane = tid & 63;
    int col  = lane & 15;
    int quad = lane >> 4;
    const int sc = 0x7F7F7F7F;             // E8M0 scale 127 -> x1.0

    // closed-form triangle decode: bid -> (ti,tj), ti <= tj < 64
    int bid = blockIdx.x;
    int ti = (int)((2.0f * NGRP + 1.0f
                    - sqrtf((2.0f * NGRP + 1.0f) * (2.0f * NGRP + 1.0f) - 8.0f * (float)bid)) * 0.5f);
    while (ti > 0 && ti * NGRP - ti * (ti - 1) / 2 > bid) --ti;
    while ((ti + 1) * NGRP - (ti + 1) * ti / 2 <= bid) ++ti;
    int tj = ti + (bid - (ti * NGRP - ti * (ti - 1) / 2));
    int diag = (ti == tj);

    int laneoff = quad * 512 + col * 32;

    // A frags: row token-tiles ti*8 + wave*2 + {0,1}
    i32x8 afr[2];
    #pragma unroll
    for (int rb = 0; rb < 2; ++rb)
        afr[rb] = load_frag32(xsw + (size_t)(ti * 8 + wave * 2 + rb) * 2048 + laneoff);

    // ALL 8 B frags upfront: 16 independent dwordx4 loads in flight
    const unsigned char* bbase = xsw + (size_t)(tj * 8) * 2048 + laneoff;
    i32x8 bf[8];
    #pragma unroll
    for (int i = 0; i < 8; ++i)
        bf[i] = load_frag32(bbase + (size_t)i * 2048);

    f32x4 rsv0 = {0.f, 0.f, 0.f, 0.f};
    f32x4 rsv1 = {0.f, 0.f, 0.f, 0.f};
    float cacc[8];

    #pragma unroll
    for (int i = 0; i < 8; ++i) {
        f32x4 d0 = __builtin_amdgcn_mfma_scale_f32_16x16x128_f8f6f4(
            afr[0], bf[i], (f32x4){0.f, 0.f, 0.f, 0.f}, 0, 0, 0, sc, 0, sc);
        f32x4 d1 = __builtin_amdgcn_mfma_scale_f32_16x16x128_f8f6f4(
            afr[1], bf[i], (f32x4){0.f, 0.f, 0.f, 0.f}, 0, 0, 0, sc, 0, sc);
        f32x4 p0 = d0 * P_C4 + P_C3;
        p0 = p0 * d0 + P_C2; p0 = p0 * d0 + P_C1; p0 = p0 * d0 + 1.0f;
        f32x4 p1 = d1 * P_C4 + P_C3;
        p1 = p1 * d1 + P_C2; p1 = p1 * d1 + P_C1; p1 = p1 * d1 + 1.0f;
        rsv0 += p0;
        rsv1 += p1;
        f32x4 cp = p0 + p1;
        cacc[i] = (cp.x + cp.y) + (cp.z + cp.w);
    }

    // ---- row-sums -> part[ti*128 + r] (post-loop atomics) ----
    #pragma unroll
    for (int m = 1; m < 16; m <<= 1) {
        #pragma unroll
        for (int r = 0; r < 4; ++r) {
            rsv0[r] += __shfl_xor(rsv0[r], m);
            rsv1[r] += __shfl_xor(rsv1[r], m);
        }
    }
    if (col == 0) {
        float* rp = part + ti * 128 + wave * 32 + quad * 4;
        #pragma unroll
        for (int r = 0; r < 4; ++r) atomicAdd(&rp[r],      rsv0[r]);
        #pragma unroll
        for (int r = 0; r < 4; ++r) atomicAdd(&rp[16 + r], rsv1[r]);
    }

    // ---- col-sums -> part[tj*128 + c] (skip on diagonal) ----
    if (!diag) {
        #pragma unroll
        for (int i = 0; i < 8; ++i) {
            float cs = cacc[i];
            cs += __shfl_xor(cs, 16);
            cs += __shfl_xor(cs, 32);      // quad==0 lanes: this wave's 32-row col-sum
            if (quad == 0)
                atomicAdd(&part[tj * 128 + i * 16 + col], cs);
        }
    }

    // ---- fused finalize: last block computes the loss ----
    __threadfence();
    __syncthreads();
    if (tid == 0) slast = (atomicAdd(counter, 1u) == NBLK - 1);
    __syncthreads();
    if (slast) {
        __threadfence();                   // acquire all part[] atomics
        if (tid < BATCH) sdia[tid] = dia[tid];
        __syncthreads();
        float acc = 0.f;
        int cnt = 0;
        for (int idx = tid; idx < M_TOK; idx += 256) {
            int b = idx >> 7;
            int tt = idx & (T_LEN - 1);
            if (tt < sdia[b] - 1) {
                acc += __logf(part[idx]) - pos[idx];
                cnt++;
            }
        }
        for (int m = 32; m; m >>= 1) {
            acc += __shfl_xor(acc, m);
            cnt += __shfl_xor(cnt, m);
        }
        if (lane == 0) { sred[wave] = acc; scnt[wave] = cnt; }
        __syncthreads();
        if (tid == 0) {
            float s = sred[0] + sred[1] + sred[2] + sred[3];
            int   c = scnt[0] + scnt[1] + scnt[2] + scnt[3];
            out[0] = s / (float)c;
        }
    }
}

extern "C" void kernel_launch(void* const* d_in, const int* in_sizes, int n_in,
                              void* d_out, int out_size, void* d_ws, size_t ws_size,
                              hipStream_t stream) {
    const float* hs  = (const float*)d_in[0];
    // d_in[1] = mask (implied by dia_lens; unused)
    const int*   dia = (const int*)d_in[2];
    float* out = (float*)d_out;

    unsigned char* xsw = (unsigned char*)d_ws;                          // 1 MB fragment-major fp8
    float* pos  = (float*)((char*)d_ws + 1048576);                      // 32 KB
    float* part = (float*)((char*)d_ws + 1048576 + 32768);              // 32 KB [8192]
    unsigned int* counter = (unsigned int*)((char*)d_ws + 1048576 + 65536);

    prep_kernel<<<M_TOK / 4, 256, 0, stream>>>(hs, xsw, pos, part, counter);
    negsum_kernel<<<NBLK, 256, 0, stream>>>(xsw, part, pos, dia, counter, out);
}

// Round 14
// 80.394 us; speedup vs baseline: 2.5063x; 2.5063x over previous
//
#include <hip/hip_runtime.h>

typedef float f32x4 __attribute__((ext_vector_type(4)));
typedef int   i32x4 __attribute__((ext_vector_type(4)));
typedef int   i32x8 __attribute__((ext_vector_type(8)));
typedef unsigned short ushort_t;

#define T_LEN 128
#define BATCH 64
#define M_TOK 8192            // BATCH * T_LEN
#define HDIM  128
#define NGRP  64              // 64 groups of 128 tokens
#define NBLK  (NGRP * (NGRP + 1) / 2)   // 2080 triangle blocks
#define SQRT_LOG2E 1.2011224087864498f  // (s*xi).(s*xj) = log2(e)*xi.xj

// 2^t Taylor deg-4 (|t| <= ~0.5: max abs err ~4e-5)
#define P_C1 0.6931471806f
#define P_C2 0.2402265070f
#define P_C3 0.0555041087f
#define P_C4 0.0096181291f

// Fragment-major layout for 16x16x128 f8f6f4 MFMA:
// xsw[T][quad][col][32B]  (strides 2048 / 512 / 32 bytes)
// = bytes [quad*32, quad*32+32) of token (16*T + col), fp8 e4m3, pre-scaled.

// Kernel A: fp8 convert into fragment-major layout + fp32-exact pos_i.
// Zeroes the completion counter only (partials are written-once, no init).
__global__ __launch_bounds__(256) void prep_kernel(const float* __restrict__ hs,
                                                   unsigned char* __restrict__ xsw,
                                                   float* __restrict__ pos,
                                                   unsigned int* __restrict__ counter) {
    int wave = threadIdx.x >> 6;
    int lane = threadIdx.x & 63;
    int i = blockIdx.x * 4 + wave;
    int t = i & (T_LEN - 1);
    const float* row = hs + (size_t)i * HDIM;
    float2 x = *(const float2*)(row + 2 * lane);
    unsigned int pk = __builtin_amdgcn_cvt_pk_fp8_f32(x.x * SQRT_LOG2E,
                                                      x.y * SQRT_LOG2E, 0, false);
    {
        int T   = i >> 4;
        int c   = i & 15;
        int qd  = lane >> 4;            // (2*lane) / 32
        int off = (2 * lane) & 31;      // within the 32B chunk (even)
        *(ushort_t*)(xsw + (size_t)T * 2048 + qd * 512 + c * 32 + off) = (ushort_t)pk;
    }
    float acc = 0.f;
    if (t > 0) {
        float2 p = *(const float2*)(row - HDIM + 2 * lane);
        acc += x.x * p.x + x.y * p.y;
    }
    if (t < T_LEN - 1) {
        float2 n = *(const float2*)(row + HDIM + 2 * lane);
        acc += x.x * n.x + x.y * n.y;
    }
    for (int m = 32; m; m >>= 1) acc += __shfl_xor(acc, m);
    if (lane == 0) pos[i] = acc;
    if (blockIdx.x == 0 && threadIdx.x == 0) counter[0] = 0u;
}

__device__ inline i32x8 load_frag32(const unsigned char* p) {
    i32x4 lo = *(const i32x4*)p;
    i32x4 hi = *(const i32x4*)(p + 16);
    return __builtin_shufflevector(lo, hi, 0, 1, 2, 3, 4, 5, 6, 7);
}

// Kernel B (R14) = R12's clean write-once structure + R13's ILP fix.
// Triangle gram: block (ti,tj), ti<=tj; wave w: 32 rows (2 A frags) x 8
// col-tiles. ALL 8 B frags (64 VGPRs) loaded upfront -> one ~400cyc
// latency exposure (R12's depth-2 ring was the leak). Closed-form decode.
// NO atomics, NO threadfence, NO fused fin (R11/R13's 145us killer).
// partials[k][token] written exactly once: row-sums -> partials[tj][Ri],
// col-sums -> partials[ti][Cj] (transposed-tile row-sums).
__global__ __launch_bounds__(256) void negsum_kernel(const unsigned char* __restrict__ xsw,
                                                     float* __restrict__ partials) {
    __shared__ float sCol[4 * 128];
    int tid  = threadIdx.x;
    int wave = tid >> 6;
    int lane = tid & 63;
    int col  = lane & 15;
    int quad = lane >> 4;
    const int sc = 0x7F7F7F7F;             // E8M0 scale 127 -> x1.0

    // closed-form triangle decode: bid -> (ti,tj), ti <= tj < 64
    int bid = blockIdx.x;
    int ti = (int)((2.0f * NGRP + 1.0f
                    - sqrtf((2.0f * NGRP + 1.0f) * (2.0f * NGRP + 1.0f) - 8.0f * (float)bid)) * 0.5f);
    while (ti > 0 && ti * NGRP - ti * (ti - 1) / 2 > bid) --ti;
    while ((ti + 1) * NGRP - (ti + 1) * ti / 2 <= bid) ++ti;
    int tj = ti + (bid - (ti * NGRP - ti * (ti - 1) / 2));
    int diag = (ti == tj);

    int laneoff = quad * 512 + col * 32;

    // A frags: row token-tiles ti*8 + wave*2 + {0,1}
    i32x8 afr[2];
    #pragma unroll
    for (int rb = 0; rb < 2; ++rb)
        afr[rb] = load_frag32(xsw + (size_t)(ti * 8 + wave * 2 + rb) * 2048 + laneoff);

    // ALL 8 B frags upfront: 16 independent dwordx4 loads in flight
    const unsigned char* bbase = xsw + (size_t)(tj * 8) * 2048 + laneoff;
    i32x8 bf[8];
    #pragma unroll
    for (int i = 0; i < 8; ++i)
        bf[i] = load_frag32(bbase + (size_t)i * 2048);

    f32x4 rsv0 = {0.f, 0.f, 0.f, 0.f};
    f32x4 rsv1 = {0.f, 0.f, 0.f, 0.f};
    float cacc[8];

    #pragma unroll
    for (int i = 0; i < 8; ++i) {
        f32x4 d0 = __builtin_amdgcn_mfma_scale_f32_16x16x128_f8f6f4(
            afr[0], bf[i], (f32x4){0.f, 0.f, 0.f, 0.f}, 0, 0, 0, sc, 0, sc);
        f32x4 d1 = __builtin_amdgcn_mfma_scale_f32_16x16x128_f8f6f4(
            afr[1], bf[i], (f32x4){0.f, 0.f, 0.f, 0.f}, 0, 0, 0, sc, 0, sc);
        f32x4 p0 = d0 * P_C4 + P_C3;
        p0 = p0 * d0 + P_C2; p0 = p0 * d0 + P_C1; p0 = p0 * d0 + 1.0f;
        f32x4 p1 = d1 * P_C4 + P_C3;
        p1 = p1 * d1 + P_C2; p1 = p1 * d1 + P_C1; p1 = p1 * d1 + 1.0f;
        rsv0 += p0;
        rsv1 += p1;
        f32x4 cp = p0 + p1;
        cacc[i] = (cp.x + cp.y) + (cp.z + cp.w);
    }

    // ---- row-sums -> partials[tj][ti*128 + r]  (write-once) ----
    #pragma unroll
    for (int m = 1; m < 16; m <<= 1) {
        #pragma unroll
        for (int r = 0; r < 4; ++r) {
            rsv0[r] += __shfl_xor(rsv0[r], m);
            rsv1[r] += __shfl_xor(rsv1[r], m);
        }
    }
    if (col == 0) {
        float* rp = partials + (size_t)tj * M_TOK + ti * 128 + wave * 32 + quad * 4;
        #pragma unroll
        for (int r = 0; r < 4; ++r) rp[r]      = rsv0[r];
        #pragma unroll
        for (int r = 0; r < 4; ++r) rp[16 + r] = rsv1[r];
    }

    // ---- col-sums -> partials[ti][tj*128 + c]  (write-once, skip diag) ----
    if (!diag) {
        #pragma unroll
        for (int i = 0; i < 8; ++i) {
            float cs = cacc[i];
            cs += __shfl_xor(cs, 16);
            cs += __shfl_xor(cs, 32);      // quad==0 lanes hold wave col-sum
            if (quad == 0)
                sCol[wave * 128 + i * 16 + col] = cs;
        }
        __syncthreads();
        if (tid < 128) {
            float v = sCol[tid] + sCol[128 + tid] + sCol[256 + tid] + sCol[384 + tid];
            partials[(size_t)ti * M_TOK + tj * 128 + tid] = v;
        }
    }
}

// Kernel C: one block per batch (128 thr); token's neg-sum = sum of its 64
// write-once partials (coalesced per k-step). Last block reduces bpart.
__global__ __launch_bounds__(128) void fin_kernel(const float* __restrict__ partials,
                                                  const float* __restrict__ pos,
                                                  const int* __restrict__ dia,
                                                  float* __restrict__ bpart,
                                                  unsigned int* __restrict__ counter,
                                                  float* __restrict__ out) {
    __shared__ float s2[2];
    __shared__ int slast;
    int b = blockIdx.x;
    int t = threadIdx.x;
    int len = dia[b];
    int i = b * T_LEN + t;
    float ns = 0.f;
    #pragma unroll 8
    for (int k = 0; k < NGRP; ++k)
        ns += partials[(size_t)k * M_TOK + i];
    float acc = (t < len - 1) ? (__logf(ns) - pos[i]) : 0.f;
    for (int m = 32; m; m >>= 1) acc += __shfl_xor(acc, m);
    if ((t & 63) == 0) s2[t >> 6] = acc;
    __syncthreads();
    if (t == 0) {
        bpart[b] = s2[0] + s2[1];
        __threadfence();                               // release bpart[b]
        slast = (atomicAdd(counter, 1u) == BATCH - 1);
    }
    __syncthreads();
    if (slast && t < 64) {
        __threadfence();                               // acquire others' bpart
        float s = bpart[t];
        int c = dia[t] - 1;
        for (int m = 32; m; m >>= 1) {
            s += __shfl_xor(s, m);
            c += __shfl_xor(c, m);
        }
        if (t == 0) out[0] = s / (float)c;
    }
}

extern "C" void kernel_launch(void* const* d_in, const int* in_sizes, int n_in,
                              void* d_out, int out_size, void* d_ws, size_t ws_size,
                              hipStream_t stream) {
    const float* hs  = (const float*)d_in[0];
    // d_in[1] = mask (implied by dia_lens; unused)
    const int*   dia = (const int*)d_in[2];
    float* out = (float*)d_out;

    unsigned char* xsw = (unsigned char*)d_ws;                          // 1 MB fragment-major fp8
    float* pos      = (float*)((char*)d_ws + 1048576);                  // 32 KB
    float* partials = (float*)((char*)d_ws + 1048576 + 32768);          // 2 MB [64][8192]
    float* bpart    = (float*)((char*)d_ws + 1048576 + 32768 + 2097152);// 256 B
    unsigned int* counter = (unsigned int*)((char*)d_ws + 1048576 + 32768 + 2097152 + 256);

    prep_kernel<<<M_TOK / 4, 256, 0, stream>>>(hs, xsw, pos, counter);
    negsum_kernel<<<NBLK, 256, 0, stream>>>(xsw, partials);
    fin_kernel<<<BATCH, 128, 0, stream>>>(partials, pos, dia, bpart, counter, out);
}